// Round 17
// baseline (143.347 us; speedup 1.0000x reference)
//
#include <hip/hip_runtime.h>
#include <hip/hip_bf16.h>
#include <hip/hip_cooperative_groups.h>
#include <math.h>

namespace cg = cooperative_groups;

#define B_   4
#define C_   64
#define N_   4096
#define L2E  1.4426950408889634f

typedef __attribute__((ext_vector_type(8)))  short bf16x8;
typedef __attribute__((ext_vector_type(4)))  float f32x4;
typedef __attribute__((ext_vector_type(16))) float f32x16;
typedef __attribute__((ext_vector_type(4)))  uint  uint4v;

#define MFMA16(a,b,c) __builtin_amdgcn_mfma_f32_16x16x32_bf16(a,b,c,0,0,0)
#define MFMA32(a,b,c) __builtin_amdgcn_mfma_f32_32x32x16_bf16(a,b,c,0,0,0)

static __device__ inline uint cvtpk(float lo, float hi) {
    uint r;
    asm("v_cvt_pk_bf16_f32 %0, %1, %2" : "=v"(r) : "v"(lo), "v"(hi));
    return r;
}
static __device__ inline void plswap(uint &a, uint &b) {
    asm("v_permlane32_swap_b32 %0, %1" : "+v"(a), "+v"(b));
}
static __device__ inline float ex2(float x) {
#if __has_builtin(__builtin_amdgcn_exp2f)
    return __builtin_amdgcn_exp2f(x);
#else
    return exp2f(x);
#endif
}
static __device__ inline float frcp(float x) {
#if __has_builtin(__builtin_amdgcn_rcpf)
    return __builtin_amdgcn_rcpf(x);
#else
    return 1.0f / x;
#endif
}
static __device__ inline float tsum16(const f32x16 &s) {
    float a0 = s[0] + s[1],  a1 = s[2] + s[3];
    float a2 = s[4] + s[5],  a3 = s[6] + s[7];
    float a4 = s[8] + s[9],  a5 = s[10] + s[11];
    float a6 = s[12] + s[13], a7 = s[14] + s[15];
    a0 += a1; a2 += a3; a4 += a5; a6 += a7;
    return (a0 + a2) + (a4 + a6);
}
static __device__ inline bf16x8 pk8(float f0, float f1, float f2, float f3,
                                    float f4, float f5, float f6, float f7) {
    uint4v u = {cvtpk(f0, f1), cvtpk(f2, f3), cvtpk(f4, f5), cvtpk(f6, f7)};
    return __builtin_bit_cast(bf16x8, u);
}

// ================= fused qkv + flash, single cooperative launch =============
// Grid 256 x 1024 = 1 block/CU (LDS 137KB, VGPR<=128) -> cooperative-safe.
// Phase 1 (qkv): block wg runs old qkv sub-blocks {wg*2, wg*2+1} (512 thr
// active). Phase 2 (flash): R15 body unchanged. grid.sync() between.
__global__ __launch_bounds__(1024, 4) void fused_attn(
    const float* __restrict__ x, const float* __restrict__ xrgb,
    const float* __restrict__ Wq, const float* __restrict__ bq,
    const float* __restrict__ Wk, const float* __restrict__ bk,
    const float* __restrict__ Wv, const float* __restrict__ bv,
    const float* __restrict__ lam,
    ushort* __restrict__ Qo, ushort* __restrict__ Ko, ushort* __restrict__ VT,
    float* __restrict__ out)
{
    __shared__ float OT[16][64][33];  // flash phase only
    __shared__ float LC[16][33];

    const int wg = blockIdx.x;

    // ---------------- phase 1: QKV projection (zero-LDS, R15 logic) --------
    if (threadIdx.x < 512) {
        const int vb = threadIdx.x >> 8;            // which old sub-block (0/1)
        const int t = threadIdx.x & 255;
        const int oldid = wg * 2 + vb;              // in [0, 512)
        const int b = oldid >> 7, n0 = (oldid & 127) * 32;
        const int w = t >> 6, lane = t & 63, li = lane & 15, g = lane >> 4;
        const int pw = w & 1, oh = w >> 1;
        const int px = n0 + pw * 16 + li;

        bf16x8 bxf[2], brf[2];
        #pragma unroll
        for (int kk = 0; kk < 2; ++kk) {
            const int c0 = kk * 32 + g * 8;
            const float* xb = x + ((size_t)b * C_ + c0) * N_ + px;
            float fx[8];
            #pragma unroll
            for (int r = 0; r < 8; ++r) fx[r] = xb[(size_t)r * N_];
            bxf[kk] = pk8(fx[0], fx[1], fx[2], fx[3], fx[4], fx[5], fx[6], fx[7]);
            if (oh == 0) {
                const float* rb = xrgb + ((size_t)b * C_ + c0) * N_ + px;
                float fr[8];
                #pragma unroll
                for (int r = 0; r < 8; ++r) fr[r] = rb[(size_t)r * N_];
                brf[kk] = pk8(fr[0], fr[1], fr[2], fr[3], fr[4], fr[5], fr[6], fr[7]);
            } else {
                brf[kk] = bxf[kk];
            }
        }

        const f32x4 cz = {0.f, 0.f, 0.f, 0.f};
        #pragma unroll
        for (int j = 0; j < 3; ++j) {
            const int ot = oh * 3 + j;
            const float* wsrc;
            const float* bsrc;
            if (ot == 0)      { wsrc = Wq + li * 64;                   bsrc = bq; }
            else if (ot == 1) { wsrc = Wk + li * 64;                   bsrc = bk; }
            else              { wsrc = Wv + ((ot - 2) * 16 + li) * 64; bsrc = bv + (ot - 2) * 16; }
            const float s = (ot == 0) ? L2E : 1.0f;   // fold log2e into Q

            f32x4 acc = cz;
            #pragma unroll
            for (int kk = 0; kk < 2; ++kk) {
                const int c0 = kk * 32 + g * 8;
                const float4 a  = *(const float4*)(wsrc + c0);
                const float4 c4 = *(const float4*)(wsrc + c0 + 4);
                const bf16x8 wa = pk8(a.x * s, a.y * s, a.z * s, a.w * s,
                                      c4.x * s, c4.y * s, c4.z * s, c4.w * s);
                acc = MFMA16(wa, (ot == 0 ? brf[kk] : bxf[kk]), acc);
            }
            const float b0 = bsrc[g * 4 + 0] * s, b1 = bsrc[g * 4 + 1] * s;
            const float b2 = bsrc[g * 4 + 2] * s, b3 = bsrc[g * 4 + 3] * s;
            if (ot < 2) {
                uint2 pwd;
                pwd.x = cvtpk(acc[0] + b0, acc[1] + b1);
                pwd.y = cvtpk(acc[2] + b2, acc[3] + b3);
                ushort* dst = (ot == 0 ? Qo : Ko) + (size_t)(b * N_ + px) * 16 + g * 4;
                *(uint2*)dst = pwd;
            } else {
                const size_t base = (((size_t)b * (N_ / 16) + (px >> 4)) * 64
                                     + (ot - 2) * 16 + g * 4) * 16 + (px & 15);
                const uint v01 = cvtpk(acc[0] + b0, acc[1] + b1);
                const uint v23 = cvtpk(acc[2] + b2, acc[3] + b3);
                VT[base]      = (ushort)(v01 & 0xffff);
                VT[base + 16] = (ushort)(v01 >> 16);
                VT[base + 32] = (ushort)(v23 & 0xffff);
                VT[base + 48] = (ushort)(v23 >> 16);
            }
        }
    }

    __threadfence();
    cg::this_grid().sync();

    // ---------------- phase 2: flash attention (R15 body, unchanged) -------
    {
        const int t = threadIdx.x, w = t >> 6, lane = t & 63;
        const int l31 = lane & 31, h = lane >> 5;
        const int qh = w & 1, jg = w >> 1;

        const int b  = wg >> 6;
        const int i0 = (wg & 63) * 64;

        const bf16x8 qf = *(const bf16x8*)(Qo + ((size_t)(b * N_ + i0 + qh * 32 + l31)) * 16 + h * 8);

        const size_t jbase = (size_t)jg * 512;
        const ushort* kp = Ko + ((size_t)(b * N_) + jbase + l31) * 16 + h * 8;
        const ushort* vt = VT + (((size_t)b * (N_ / 16) + jg * 32) * 64 + l31) * 16 + h * 8;

        f32x16 a0, a1, z16;
        #pragma unroll
        for (int i = 0; i < 16; ++i) { a0[i] = 0.f; a1[i] = 0.f; z16[i] = 0.f; }
        float lsum = 0.f;

        #pragma unroll 1
        for (int jt = 0; jt < 16; ++jt) {
            const bf16x8 kf = *(const bf16x8*)(kp + (size_t)jt * 512);

            f32x16 st = MFMA32(kf, qf, z16);
            #pragma unroll
            for (int i = 0; i < 16; ++i) st[i] = ex2(st[i]);   // raw 2^s
            lsum += tsum16(st);

            uint A0 = cvtpk(st[0],  st[1]),  A1 = cvtpk(st[2],  st[3]);
            uint B0 = cvtpk(st[4],  st[5]),  B1 = cvtpk(st[6],  st[7]);
            uint C0 = cvtpk(st[8],  st[9]),  C1 = cvtpk(st[10], st[11]);
            uint D0 = cvtpk(st[12], st[13]), D1 = cvtpk(st[14], st[15]);
            plswap(A0, B0); plswap(A1, B1); plswap(C0, D0); plswap(C1, D1);
            uint4v u0 = {A0, A1, B0, B1}, u1 = {C0, C1, D0, D1};
            const bf16x8 pf0 = __builtin_bit_cast(bf16x8, u0);
            const bf16x8 pf1 = __builtin_bit_cast(bf16x8, u1);

            const ushort* vtj = vt + (size_t)jt * 2048;
            {
                const bf16x8 va = *(const bf16x8*)(vtj);
                const bf16x8 vb = *(const bf16x8*)(vtj + 512);
                a0 = MFMA32(va, pf0, a0);
                a1 = MFMA32(vb, pf0, a1);
            }
            {
                const bf16x8 va = *(const bf16x8*)(vtj + 1024);
                const bf16x8 vb = *(const bf16x8*)(vtj + 1536);
                a0 = MFMA32(va, pf1, a0);
                a1 = MFMA32(vb, pf1, a1);
            }
        }

        lsum += __shfl_xor(lsum, 32);
        if (h == 0) LC[w][l31] = lsum;

        #pragma unroll
        for (int r = 0; r < 16; ++r) {
            const int c = (r & 3) + 8 * (r >> 2) + 4 * h;
            OT[w][c][l31]      = a0[r];
            OT[w][c + 32][l31] = a1[r];
        }
        __syncthreads();

        {
            const int qh2 = t >> 9, c = (t >> 3) & 63, q0 = (t & 7) * 4;
            const float la = lam[0];
            f32x4 o = {0.f, 0.f, 0.f, 0.f};
            f32x4 ls = {0.f, 0.f, 0.f, 0.f};
            #pragma unroll
            for (int p = 0; p < 8; ++p) {
                const int idx = p * 2 + qh2;
                const f32x4 v = *(const f32x4*)&OT[idx][c][q0];
                o[0] += v[0]; o[1] += v[1]; o[2] += v[2]; o[3] += v[3];
                #pragma unroll
                for (int k = 0; k < 4; ++k) ls[k] += LC[idx][q0 + k];
            }
            const size_t off = ((size_t)b * C_ + c) * N_ + i0 + qh2 * 32 + q0;
            const float4 xv = *(const float4*)(x + off);
            float4 res;
            res.x = la * o[0] * frcp(ls[0]) + xv.x;
            res.y = la * o[1] * frcp(ls[1]) + xv.y;
            res.z = la * o[2] * frcp(ls[2]) + xv.z;
            res.w = la * o[3] * frcp(ls[3]) + xv.w;
            *(float4*)(out + off) = res;
        }
    }
}

extern "C" void kernel_launch(void* const* d_in, const int* in_sizes, int n_in,
                              void* d_out, int out_size, void* d_ws, size_t ws_size,
                              hipStream_t stream)
{
    (void)in_sizes; (void)n_in; (void)out_size; (void)ws_size;
    const float* x    = (const float*)d_in[0];
    const float* xrgb = (const float*)d_in[1];
    const float* Wq   = (const float*)d_in[2];
    const float* bq   = (const float*)d_in[3];
    const float* Wk   = (const float*)d_in[4];
    const float* bk   = (const float*)d_in[5];
    const float* Wv   = (const float*)d_in[6];
    const float* bv   = (const float*)d_in[7];
    const float* lam  = (const float*)d_in[8];
    float* out = (float*)d_out;

    // workspace (bf16): Q 512KB | K 512KB | VT 2MB — all fully overwritten
    ushort* Qw = (ushort*)d_ws;                       // [B][N][16]
    ushort* Kw = Qw + (size_t)B_ * N_ * 16;           // [B][N][16]
    ushort* Vw = Kw + (size_t)B_ * N_ * 16;           // VT[B][N/16][64][16]

    void* args[] = {
        (void*)&x, (void*)&xrgb, (void*)&Wq, (void*)&bq, (void*)&Wk,
        (void*)&bk, (void*)&Wv, (void*)&bv, (void*)&lam,
        (void*)&Qw, (void*)&Kw, (void*)&Vw, (void*)&out
    };
    hipLaunchCooperativeKernel((const void*)fused_attn, dim3(256), dim3(1024),
                               args, 0, stream);
}

// Round 18
// 32.577 us; speedup vs baseline: 4.4002x; 4.4002x over previous
//
#include <hip/hip_runtime.h>
#include <hip/hip_bf16.h>
#include <math.h>

#define B_   4
#define C_   64
#define N_   4096
#define L2E  1.4426950408889634f

typedef __attribute__((ext_vector_type(8)))  short bf16x8;
typedef __attribute__((ext_vector_type(4)))  float f32x4;
typedef __attribute__((ext_vector_type(16))) float f32x16;
typedef __attribute__((ext_vector_type(4)))  uint  uint4v;

#define MFMA16(a,b,c) __builtin_amdgcn_mfma_f32_16x16x32_bf16(a,b,c,0,0,0)
#define MFMA32(a,b,c) __builtin_amdgcn_mfma_f32_32x32x16_bf16(a,b,c,0,0,0)

static __device__ inline uint cvtpk(float lo, float hi) {
    uint r;
    asm("v_cvt_pk_bf16_f32 %0, %1, %2" : "=v"(r) : "v"(lo), "v"(hi));
    return r;
}
static __device__ inline void plswap(uint &a, uint &b) {
    asm("v_permlane32_swap_b32 %0, %1" : "+v"(a), "+v"(b));
}
static __device__ inline float ex2(float x) {
#if __has_builtin(__builtin_amdgcn_exp2f)
    return __builtin_amdgcn_exp2f(x);   // raw v_exp_f32, compiler-scheduled
#else
    return exp2f(x);
#endif
}
static __device__ inline float frcp(float x) {
#if __has_builtin(__builtin_amdgcn_rcpf)
    return __builtin_amdgcn_rcpf(x);
#else
    return 1.0f / x;
#endif
}
static __device__ inline float tsum16(const f32x16 &s) {
    float a0 = s[0] + s[1],  a1 = s[2] + s[3];
    float a2 = s[4] + s[5],  a3 = s[6] + s[7];
    float a4 = s[8] + s[9],  a5 = s[10] + s[11];
    float a6 = s[12] + s[13], a7 = s[14] + s[15];
    a0 += a1; a2 += a3; a4 += a5; a6 += a7;
    return (a0 + a2) + (a4 + a6);
}
static __device__ inline bf16x8 pk8(float f0, float f1, float f2, float f3,
                                    float f4, float f5, float f6, float f7) {
    uint4v u = {cvtpk(f0, f1), cvtpk(f2, f3), cvtpk(f4, f5), cvtpk(f6, f7)};
    return __builtin_bit_cast(bf16x8, u);
}
// P (f32x16 C/D of energy) -> two bf16 B-fragments, in-register (T12)
static __device__ inline void pack_p(const f32x16 &st, bf16x8 &pf0, bf16x8 &pf1) {
    uint A0 = cvtpk(st[0],  st[1]),  A1 = cvtpk(st[2],  st[3]);
    uint B0 = cvtpk(st[4],  st[5]),  B1 = cvtpk(st[6],  st[7]);
    uint C0 = cvtpk(st[8],  st[9]),  C1 = cvtpk(st[10], st[11]);
    uint D0 = cvtpk(st[12], st[13]), D1 = cvtpk(st[14], st[15]);
    plswap(A0, B0); plswap(A1, B1); plswap(C0, D0); plswap(C1, D1);
    uint4v u0 = {A0, A1, B0, B1}, u1 = {C0, C1, D0, D1};
    pf0 = __builtin_bit_cast(bf16x8, u0);
    pf1 = __builtin_bit_cast(bf16x8, u1);
}

// ---------------- QKV projection: zero-LDS, zero-barrier (R15, unchanged) --
__global__ __launch_bounds__(256) void qkv_mfma(
    const float* __restrict__ x, const float* __restrict__ xrgb,
    const float* __restrict__ Wq, const float* __restrict__ bq,
    const float* __restrict__ Wk, const float* __restrict__ bk,
    const float* __restrict__ Wv, const float* __restrict__ bv,
    ushort* __restrict__ Qo, ushort* __restrict__ Ko, ushort* __restrict__ Vo)
{
    const int t = threadIdx.x, b = blockIdx.y, n0 = blockIdx.x * 32;
    const int w = t >> 6, lane = t & 63, li = lane & 15, g = lane >> 4;
    const int pw = w & 1, oh = w >> 1;
    const int px = n0 + pw * 16 + li;

    bf16x8 bxf[2], brf[2];
    #pragma unroll
    for (int kk = 0; kk < 2; ++kk) {
        const int c0 = kk * 32 + g * 8;
        const float* xb = x + ((size_t)b * C_ + c0) * N_ + px;
        float fx[8];
        #pragma unroll
        for (int r = 0; r < 8; ++r) fx[r] = xb[(size_t)r * N_];
        bxf[kk] = pk8(fx[0], fx[1], fx[2], fx[3], fx[4], fx[5], fx[6], fx[7]);
        if (oh == 0) {
            const float* rb = xrgb + ((size_t)b * C_ + c0) * N_ + px;
            float fr[8];
            #pragma unroll
            for (int r = 0; r < 8; ++r) fr[r] = rb[(size_t)r * N_];
            brf[kk] = pk8(fr[0], fr[1], fr[2], fr[3], fr[4], fr[5], fr[6], fr[7]);
        } else {
            brf[kk] = bxf[kk];
        }
    }

    const f32x4 cz = {0.f, 0.f, 0.f, 0.f};
    #pragma unroll
    for (int j = 0; j < 3; ++j) {
        const int ot = oh * 3 + j;
        const float* wsrc;
        const float* bsrc;
        if (ot == 0)      { wsrc = Wq + li * 64;                   bsrc = bq; }
        else if (ot == 1) { wsrc = Wk + li * 64;                   bsrc = bk; }
        else              { wsrc = Wv + ((ot - 2) * 16 + li) * 64; bsrc = bv + (ot - 2) * 16; }
        const float s = (ot == 0) ? L2E : 1.0f;   // fold log2e into Q

        f32x4 acc = cz;
        #pragma unroll
        for (int kk = 0; kk < 2; ++kk) {
            const int c0 = kk * 32 + g * 8;
            const float4 a  = *(const float4*)(wsrc + c0);
            const float4 c4 = *(const float4*)(wsrc + c0 + 4);
            const bf16x8 wa = pk8(a.x * s, a.y * s, a.z * s, a.w * s,
                                  c4.x * s, c4.y * s, c4.z * s, c4.w * s);
            acc = MFMA16(wa, (ot == 0 ? brf[kk] : bxf[kk]), acc);
        }
        const float b0 = bsrc[g * 4 + 0] * s, b1 = bsrc[g * 4 + 1] * s;
        const float b2 = bsrc[g * 4 + 2] * s, b3 = bsrc[g * 4 + 3] * s;
        if (ot < 2) {
            uint2 pwd;
            pwd.x = cvtpk(acc[0] + b0, acc[1] + b1);
            pwd.y = cvtpk(acc[2] + b2, acc[3] + b3);
            ushort* dst = (ot == 0 ? Qo : Ko) + (size_t)(b * N_ + px) * 16 + g * 4;
            *(uint2*)dst = pwd;
        } else {
            const size_t base = (((size_t)b * (N_ / 16) + (px >> 4)) * 64
                                 + (ot - 2) * 16 + g * 4) * 16 + (px & 15);
            const uint v01 = cvtpk(acc[0] + b0, acc[1] + b1);
            const uint v23 = cvtpk(acc[2] + b2, acc[3] + b3);
            Vo[base]      = (ushort)(v01 & 0xffff);
            Vo[base + 16] = (ushort)(v01 >> 16);
            Vo[base + 32] = (ushort)(v23 & 0xffff);
            Vo[base + 48] = (ushort)(v23 >> 16);
        }
    }
}

// ---------------- flash attention: Q-pairing x 16 waves --------------------
// 256 blocks x 1024 thr; wave w = key-group (256 keys, 8 tiles of 32). Each
// wave holds TWO Q-fragments (queries i0+l31, i0+32+l31) and reuses every
// K/V fragment for both -> L2 fragment traffic HALVES (~168MB, ~5us floor).
// No-shift softmax (raw v_exp_f32, pure-sum merge; validated R12-R15).
// Merge: two sequential 16-partial sum-rounds through the OT overlay.
__global__ __launch_bounds__(1024, 4) void flash32(
    const ushort* __restrict__ Qg, const ushort* __restrict__ Kg,
    const ushort* __restrict__ VT, const float* __restrict__ x,
    const float* __restrict__ lam, float* __restrict__ out)
{
    __shared__ float OT[16][64][33];  // 135168 B, reused across 2 rounds
    __shared__ float LC[2][16][33];   // 4224 B

    const int t = threadIdx.x, w = t >> 6, lane = t & 63;
    const int l31 = lane & 31, h = lane >> 5;

    const int wg = blockIdx.x;
    const int b  = wg >> 6;
    const int i0 = (wg & 63) * 64;

    // two Q fragments (B op: col=q, k=c=h*8+r)
    const bf16x8 qfA = *(const bf16x8*)(Qg + ((size_t)(b * N_ + i0 + l31)) * 16 + h * 8);
    const bf16x8 qfB = *(const bf16x8*)(Qg + ((size_t)(b * N_ + i0 + 32 + l31)) * 16 + h * 8);

    const size_t jbase = (size_t)w * 256;            // 16 key-groups of 256
    const ushort* kp = Kg + ((size_t)(b * N_) + jbase + l31) * 16 + h * 8;
    const ushort* vt = VT + (((size_t)b * (N_ / 16) + w * 16) * 64 + l31) * 16 + h * 8;

    f32x16 aA0, aA1, aB0, aB1, z16;
    #pragma unroll
    for (int i = 0; i < 16; ++i) {
        aA0[i] = 0.f; aA1[i] = 0.f; aB0[i] = 0.f; aB1[i] = 0.f; z16[i] = 0.f;
    }
    float lA = 0.f, lB = 0.f;

    #pragma unroll 1
    for (int jt = 0; jt < 8; ++jt) {                 // 8 tiles of 32 keys
        const bf16x8 kf = *(const bf16x8*)(kp + (size_t)jt * 512);
        const ushort* vtj = vt + (size_t)jt * 2048;
        const bf16x8 va0 = *(const bf16x8*)(vtj);          // c=l31,    j 0..15
        const bf16x8 vb0 = *(const bf16x8*)(vtj + 512);    // c=32+l31, j 0..15
        const bf16x8 va1 = *(const bf16x8*)(vtj + 1024);   // c=l31,    j 16..31
        const bf16x8 vb1 = *(const bf16x8*)(vtj + 1536);   // c=32+l31, j 16..31

        // ---- half A ----
        {
            f32x16 st = MFMA32(kf, qfA, z16);
            #pragma unroll
            for (int i = 0; i < 16; ++i) st[i] = ex2(st[i]);   // raw 2^s
            lA += tsum16(st);
            bf16x8 pf0, pf1;
            pack_p(st, pf0, pf1);
            aA0 = MFMA32(va0, pf0, aA0);
            aA1 = MFMA32(vb0, pf0, aA1);
            aA0 = MFMA32(va1, pf1, aA0);
            aA1 = MFMA32(vb1, pf1, aA1);
        }
        // ---- half B (reuses kf + V fragments) ----
        {
            f32x16 st = MFMA32(kf, qfB, z16);
            #pragma unroll
            for (int i = 0; i < 16; ++i) st[i] = ex2(st[i]);
            lB += tsum16(st);
            bf16x8 pf0, pf1;
            pack_p(st, pf0, pf1);
            aB0 = MFMA32(va0, pf0, aB0);
            aB1 = MFMA32(vb0, pf0, aB1);
            aB0 = MFMA32(va1, pf1, aB0);
            aB1 = MFMA32(vb1, pf1, aB1);
        }
    }

    // per-query l: combine the two C/D row-halves (h=0/1)
    lA += __shfl_xor(lA, 32);
    lB += __shfl_xor(lB, 32);
    if (h == 0) { LC[0][w][l31] = lA; LC[1][w][l31] = lB; }

    const float la = lam[0];

    // ---- round A: queries i0..i0+31, sum 16 partials ----
    #pragma unroll
    for (int r = 0; r < 16; ++r) {
        const int c = (r & 3) + 8 * (r >> 2) + 4 * h;
        OT[w][c][l31]      = aA0[r];
        OT[w][c + 32][l31] = aA1[r];
    }
    __syncthreads();
    {
        const int c = t >> 4, qd = (t & 15) * 2;
        float o0 = 0.f, o1 = 0.f, l0 = 0.f, l1 = 0.f;
        #pragma unroll
        for (int p = 0; p < 16; ++p) {
            o0 += OT[p][c][qd];     o1 += OT[p][c][qd + 1];
            l0 += LC[0][p][qd];     l1 += LC[0][p][qd + 1];
        }
        const size_t off = ((size_t)b * C_ + c) * N_ + i0 + qd;
        const float2 xv = *(const float2*)(x + off);
        float2 res;
        res.x = la * o0 * frcp(l0) + xv.x;
        res.y = la * o1 * frcp(l1) + xv.y;
        *(float2*)(out + off) = res;
    }
    __syncthreads();

    // ---- round B: queries i0+32..i0+63 ----
    #pragma unroll
    for (int r = 0; r < 16; ++r) {
        const int c = (r & 3) + 8 * (r >> 2) + 4 * h;
        OT[w][c][l31]      = aB0[r];
        OT[w][c + 32][l31] = aB1[r];
    }
    __syncthreads();
    {
        const int c = t >> 4, qd = (t & 15) * 2;
        float o0 = 0.f, o1 = 0.f, l0 = 0.f, l1 = 0.f;
        #pragma unroll
        for (int p = 0; p < 16; ++p) {
            o0 += OT[p][c][qd];     o1 += OT[p][c][qd + 1];
            l0 += LC[1][p][qd];     l1 += LC[1][p][qd + 1];
        }
        const size_t off = ((size_t)b * C_ + c) * N_ + i0 + 32 + qd;
        const float2 xv = *(const float2*)(x + off);
        float2 res;
        res.x = la * o0 * frcp(l0) + xv.x;
        res.y = la * o1 * frcp(l1) + xv.y;
        *(float2*)(out + off) = res;
    }
}

extern "C" void kernel_launch(void* const* d_in, const int* in_sizes, int n_in,
                              void* d_out, int out_size, void* d_ws, size_t ws_size,
                              hipStream_t stream)
{
    (void)in_sizes; (void)n_in; (void)out_size; (void)ws_size;
    const float* x    = (const float*)d_in[0];
    const float* xrgb = (const float*)d_in[1];
    const float* Wq   = (const float*)d_in[2];
    const float* bq   = (const float*)d_in[3];
    const float* Wk   = (const float*)d_in[4];
    const float* bk   = (const float*)d_in[5];
    const float* Wv   = (const float*)d_in[6];
    const float* bv   = (const float*)d_in[7];
    const float* lam  = (const float*)d_in[8];
    float* out = (float*)d_out;

    // workspace (bf16): Q 512KB | K 512KB | VT 2MB — all fully overwritten
    ushort* Qw = (ushort*)d_ws;                       // [B][N][16]
    ushort* Kw = Qw + (size_t)B_ * N_ * 16;           // [B][N][16]
    ushort* Vw = Kw + (size_t)B_ * N_ * 16;           // VT[B][N/16][64][16]

    qkv_mfma<<<dim3(N_ / 32, B_), 256, 0, stream>>>(
        x, xrgb, Wq, bq, Wk, bk, Wv, bv, Qw, Kw, Vw);

    flash32<<<dim3(256), 1024, 0, stream>>>(
        Qw, Kw, Vw, x, lam, out);
}

// Round 19
// 29.902 us; speedup vs baseline: 4.7939x; 1.0895x over previous
//
#include <hip/hip_runtime.h>
#include <hip/hip_bf16.h>
#include <math.h>

#define B_   4
#define C_   64
#define N_   4096
#define L2E  1.4426950408889634f

typedef __attribute__((ext_vector_type(8)))  short bf16x8;
typedef __attribute__((ext_vector_type(4)))  float f32x4;
typedef __attribute__((ext_vector_type(16))) float f32x16;
typedef __attribute__((ext_vector_type(4)))  uint  uint4v;

#define MFMA16(a,b,c) __builtin_amdgcn_mfma_f32_16x16x32_bf16(a,b,c,0,0,0)
#define MFMA32(a,b,c) __builtin_amdgcn_mfma_f32_32x32x16_bf16(a,b,c,0,0,0)

static __device__ inline uint cvtpk(float lo, float hi) {
    uint r;
    asm("v_cvt_pk_bf16_f32 %0, %1, %2" : "=v"(r) : "v"(lo), "v"(hi));
    return r;
}
static __device__ inline void plswap(uint &a, uint &b) {
    asm("v_permlane32_swap_b32 %0, %1" : "+v"(a), "+v"(b));
}
static __device__ inline float ex2(float x) {
#if __has_builtin(__builtin_amdgcn_exp2f)
    return __builtin_amdgcn_exp2f(x);   // raw v_exp_f32, compiler-scheduled
#else
    return exp2f(x);
#endif
}
static __device__ inline float frcp(float x) {
#if __has_builtin(__builtin_amdgcn_rcpf)
    return __builtin_amdgcn_rcpf(x);
#else
    return 1.0f / x;
#endif
}
static __device__ inline float tsum16(const f32x16 &s) {
    float a0 = s[0] + s[1],  a1 = s[2] + s[3];
    float a2 = s[4] + s[5],  a3 = s[6] + s[7];
    float a4 = s[8] + s[9],  a5 = s[10] + s[11];
    float a6 = s[12] + s[13], a7 = s[14] + s[15];
    a0 += a1; a2 += a3; a4 += a5; a6 += a7;
    return (a0 + a2) + (a4 + a6);
}
static __device__ inline bf16x8 pk8(float f0, float f1, float f2, float f3,
                                    float f4, float f5, float f6, float f7) {
    uint4v u = {cvtpk(f0, f1), cvtpk(f2, f3), cvtpk(f4, f5), cvtpk(f6, f7)};
    return __builtin_bit_cast(bf16x8, u);
}
// P (f32x16 C/D of energy) -> two bf16 B-fragments, in-register (T12)
static __device__ inline void pack_p(const f32x16 &st, bf16x8 &pf0, bf16x8 &pf1) {
    uint A0 = cvtpk(st[0],  st[1]),  A1 = cvtpk(st[2],  st[3]);
    uint B0 = cvtpk(st[4],  st[5]),  B1 = cvtpk(st[6],  st[7]);
    uint C0 = cvtpk(st[8],  st[9]),  C1 = cvtpk(st[10], st[11]);
    uint D0 = cvtpk(st[12], st[13]), D1 = cvtpk(st[14], st[15]);
    plswap(A0, B0); plswap(A1, B1); plswap(C0, D0); plswap(C1, D1);
    uint4v u0 = {A0, A1, B0, B1}, u1 = {C0, C1, D0, D1};
    pf0 = __builtin_bit_cast(bf16x8, u0);
    pf1 = __builtin_bit_cast(bf16x8, u1);
}

// ---------------- QKV projection: zero-LDS, zero-barrier (R15, unchanged) --
__global__ __launch_bounds__(256) void qkv_mfma(
    const float* __restrict__ x, const float* __restrict__ xrgb,
    const float* __restrict__ Wq, const float* __restrict__ bq,
    const float* __restrict__ Wk, const float* __restrict__ bk,
    const float* __restrict__ Wv, const float* __restrict__ bv,
    ushort* __restrict__ Qo, ushort* __restrict__ Ko, ushort* __restrict__ Vo)
{
    const int t = threadIdx.x, b = blockIdx.y, n0 = blockIdx.x * 32;
    const int w = t >> 6, lane = t & 63, li = lane & 15, g = lane >> 4;
    const int pw = w & 1, oh = w >> 1;
    const int px = n0 + pw * 16 + li;

    bf16x8 bxf[2], brf[2];
    #pragma unroll
    for (int kk = 0; kk < 2; ++kk) {
        const int c0 = kk * 32 + g * 8;
        const float* xb = x + ((size_t)b * C_ + c0) * N_ + px;
        float fx[8];
        #pragma unroll
        for (int r = 0; r < 8; ++r) fx[r] = xb[(size_t)r * N_];
        bxf[kk] = pk8(fx[0], fx[1], fx[2], fx[3], fx[4], fx[5], fx[6], fx[7]);
        if (oh == 0) {
            const float* rb = xrgb + ((size_t)b * C_ + c0) * N_ + px;
            float fr[8];
            #pragma unroll
            for (int r = 0; r < 8; ++r) fr[r] = rb[(size_t)r * N_];
            brf[kk] = pk8(fr[0], fr[1], fr[2], fr[3], fr[4], fr[5], fr[6], fr[7]);
        } else {
            brf[kk] = bxf[kk];
        }
    }

    const f32x4 cz = {0.f, 0.f, 0.f, 0.f};
    #pragma unroll
    for (int j = 0; j < 3; ++j) {
        const int ot = oh * 3 + j;
        const float* wsrc;
        const float* bsrc;
        if (ot == 0)      { wsrc = Wq + li * 64;                   bsrc = bq; }
        else if (ot == 1) { wsrc = Wk + li * 64;                   bsrc = bk; }
        else              { wsrc = Wv + ((ot - 2) * 16 + li) * 64; bsrc = bv + (ot - 2) * 16; }
        const float s = (ot == 0) ? L2E : 1.0f;   // fold log2e into Q

        f32x4 acc = cz;
        #pragma unroll
        for (int kk = 0; kk < 2; ++kk) {
            const int c0 = kk * 32 + g * 8;
            const float4 a  = *(const float4*)(wsrc + c0);
            const float4 c4 = *(const float4*)(wsrc + c0 + 4);
            const bf16x8 wa = pk8(a.x * s, a.y * s, a.z * s, a.w * s,
                                  c4.x * s, c4.y * s, c4.z * s, c4.w * s);
            acc = MFMA16(wa, (ot == 0 ? brf[kk] : bxf[kk]), acc);
        }
        const float b0 = bsrc[g * 4 + 0] * s, b1 = bsrc[g * 4 + 1] * s;
        const float b2 = bsrc[g * 4 + 2] * s, b3 = bsrc[g * 4 + 3] * s;
        if (ot < 2) {
            uint2 pwd;
            pwd.x = cvtpk(acc[0] + b0, acc[1] + b1);
            pwd.y = cvtpk(acc[2] + b2, acc[3] + b3);
            ushort* dst = (ot == 0 ? Qo : Ko) + (size_t)(b * N_ + px) * 16 + g * 4;
            *(uint2*)dst = pwd;
        } else {
            const size_t base = (((size_t)b * (N_ / 16) + (px >> 4)) * 64
                                 + (ot - 2) * 16 + g * 4) * 16 + (px & 15);
            const uint v01 = cvtpk(acc[0] + b0, acc[1] + b1);
            const uint v23 = cvtpk(acc[2] + b2, acc[3] + b3);
            Vo[base]      = (ushort)(v01 & 0xffff);
            Vo[base + 16] = (ushort)(v01 >> 16);
            Vo[base + 32] = (ushort)(v23 & 0xffff);
            Vo[base + 48] = (ushort)(v23 >> 16);
        }
    }
}

// ---------------- flash attention: R15 + depth-2 register prefetch ---------
// 256 blocks x 1024 thr; wave w = (qh = w&1) x (jg = w>>1, 512 keys, 16
// tiles of 32). R14/R18 evidence: not L2-BW-bound, VALU issue ~3us model vs
// 13.6us measured -> exposed L2 latency on the per-tile 5-fragment load at
// the head of the serial tile chain. Fix: rotate a prefetched fragment set
// (loads for jt+1 issued before computing jt; +20 VGPR, 60->~85 < 128 cap).
__global__ __launch_bounds__(1024, 4) void flash32(
    const ushort* __restrict__ Qg, const ushort* __restrict__ Kg,
    const ushort* __restrict__ VT, const float* __restrict__ x,
    const float* __restrict__ lam, float* __restrict__ out)
{
    __shared__ float OT[16][64][33];  // [qh*8+jg][c][q] partial O
    __shared__ float LC[16][33];      // partial l

    const int t = threadIdx.x, w = t >> 6, lane = t & 63;
    const int l31 = lane & 31, h = lane >> 5;
    const int qh = w & 1, jg = w >> 1;

    const int wg = blockIdx.x;
    const int b  = wg >> 6;
    const int i0 = (wg & 63) * 64;

    const bf16x8 qf = *(const bf16x8*)(Qg + ((size_t)(b * N_ + i0 + qh * 32 + l31)) * 16 + h * 8);

    const size_t jbase = (size_t)jg * 512;
    const ushort* kp = Kg + ((size_t)(b * N_) + jbase + l31) * 16 + h * 8;
    const ushort* vt = VT + (((size_t)b * (N_ / 16) + jg * 32) * 64 + l31) * 16 + h * 8;

    f32x16 a0, a1, z16;
    #pragma unroll
    for (int i = 0; i < 16; ++i) { a0[i] = 0.f; a1[i] = 0.f; z16[i] = 0.f; }
    float lsum = 0.f;

    // one tile's compute, all operands in registers
    auto tile_body = [&](const bf16x8 &kf, const bf16x8 &va0, const bf16x8 &vb0,
                         const bf16x8 &va1, const bf16x8 &vb1) {
        f32x16 st = MFMA32(kf, qf, z16);
        #pragma unroll
        for (int i = 0; i < 16; ++i) st[i] = ex2(st[i]);   // raw 2^s (no shift)
        lsum += tsum16(st);
        bf16x8 pf0, pf1;
        pack_p(st, pf0, pf1);
        a0 = MFMA32(va0, pf0, a0);
        a1 = MFMA32(vb0, pf0, a1);
        a0 = MFMA32(va1, pf1, a0);
        a1 = MFMA32(vb1, pf1, a1);
    };

    // prologue: load tile 0
    bf16x8 kf  = *(const bf16x8*)(kp);
    bf16x8 va0 = *(const bf16x8*)(vt);
    bf16x8 vb0 = *(const bf16x8*)(vt + 512);
    bf16x8 va1 = *(const bf16x8*)(vt + 1024);
    bf16x8 vb1 = *(const bf16x8*)(vt + 1536);

    #pragma unroll 1
    for (int jt = 0; jt < 15; ++jt) {
        // issue tile jt+1 loads (retire under tile jt's compute chain)
        const bf16x8 kfn  = *(const bf16x8*)(kp + (size_t)(jt + 1) * 512);
        const ushort* vtn = vt + (size_t)(jt + 1) * 2048;
        const bf16x8 va0n = *(const bf16x8*)(vtn);
        const bf16x8 vb0n = *(const bf16x8*)(vtn + 512);
        const bf16x8 va1n = *(const bf16x8*)(vtn + 1024);
        const bf16x8 vb1n = *(const bf16x8*)(vtn + 1536);

        tile_body(kf, va0, vb0, va1, vb1);

        kf = kfn; va0 = va0n; vb0 = vb0n; va1 = va1n; vb1 = vb1n;
    }
    tile_body(kf, va0, vb0, va1, vb1);   // epilogue tile 15

    lsum += __shfl_xor(lsum, 32);
    if (h == 0) LC[w][l31] = lsum;

    #pragma unroll
    for (int r = 0; r < 16; ++r) {
        const int c = (r & 3) + 8 * (r >> 2) + 4 * h;
        OT[w][c][l31]      = a0[r];
        OT[w][c + 32][l31] = a1[r];
    }
    __syncthreads();

    // ---- single-round merge: thread -> (qh2, c, 4 queries) ----
    {
        const int qh2 = t >> 9, c = (t >> 3) & 63, q0 = (t & 7) * 4;
        const float la = lam[0];
        f32x4 o = {0.f, 0.f, 0.f, 0.f};
        f32x4 ls = {0.f, 0.f, 0.f, 0.f};
        #pragma unroll
        for (int p = 0; p < 8; ++p) {
            const int idx = p * 2 + qh2;
            const f32x4 v = *(const f32x4*)&OT[idx][c][q0];
            o[0] += v[0]; o[1] += v[1]; o[2] += v[2]; o[3] += v[3];
            #pragma unroll
            for (int k = 0; k < 4; ++k) ls[k] += LC[idx][q0 + k];
        }
        const size_t off = ((size_t)b * C_ + c) * N_ + i0 + qh2 * 32 + q0;
        const float4 xv = *(const float4*)(x + off);
        float4 res;
        res.x = la * o[0] * frcp(ls[0]) + xv.x;
        res.y = la * o[1] * frcp(ls[1]) + xv.y;
        res.z = la * o[2] * frcp(ls[2]) + xv.z;
        res.w = la * o[3] * frcp(ls[3]) + xv.w;
        *(float4*)(out + off) = res;
    }
}

extern "C" void kernel_launch(void* const* d_in, const int* in_sizes, int n_in,
                              void* d_out, int out_size, void* d_ws, size_t ws_size,
                              hipStream_t stream)
{
    (void)in_sizes; (void)n_in; (void)out_size; (void)ws_size;
    const float* x    = (const float*)d_in[0];
    const float* xrgb = (const float*)d_in[1];
    const float* Wq   = (const float*)d_in[2];
    const float* bq   = (const float*)d_in[3];
    const float* Wk   = (const float*)d_in[4];
    const float* bk   = (const float*)d_in[5];
    const float* Wv   = (const float*)d_in[6];
    const float* bv   = (const float*)d_in[7];
    const float* lam  = (const float*)d_in[8];
    float* out = (float*)d_out;

    // workspace (bf16): Q 512KB | K 512KB | VT 2MB — all fully overwritten
    ushort* Qw = (ushort*)d_ws;                       // [B][N][16]
    ushort* Kw = Qw + (size_t)B_ * N_ * 16;           // [B][N][16]
    ushort* Vw = Kw + (size_t)B_ * N_ * 16;           // VT[B][N/16][64][16]

    qkv_mfma<<<dim3(N_ / 32, B_), 256, 0, stream>>>(
        x, xrgb, Wq, bq, Wk, bk, Wv, bv, Qw, Kw, Vw);

    flash32<<<dim3(256), 1024, 0, stream>>>(
        Qw, Kw, Vw, x, lam, out);
}